// Round 10
// baseline (85.243 us; speedup 1.0000x reference)
//
#include <hip/hip_runtime.h>

typedef int   int4v  __attribute__((ext_vector_type(4)));
typedef char  char8v __attribute__((ext_vector_type(8)));

#define NROWS 8192
#define DIM 512
#define ROWB 512           // DIM * 1 byte (i8)
#define NT 4               // K-steps of BK=128
#define SWEEP 4            // col-tiles of 64 per block

#define AS1(p) ((const __attribute__((address_space(1))) void*)(p))
#define AS3(p) ((__attribute__((address_space(3))) void*)(p))

#if __has_builtin(__builtin_amdgcn_exp2f)
#define EXP2(x) __builtin_amdgcn_exp2f(x)
#else
#define EXP2(x) exp2f(x)
#endif

// ---------------------------------------------------------------------------
// Kernel 1: wave-per-row normalize + i8 quantize + diag + rowsum zero.
// V-side is written PACKED in MFMA-fragment order (Apack) so simsum can load
// A-frags from global with perfectly-coalesced base+lane*16 addresses:
//   frag block (rowgrp g = r/16, kstep t = k/128, half kk = (k/64)&1) is
//   1024 B: lane l = ((k>>4)&3)*16 + (r&15) holds bytes k_local = l>>4 chunk.
// U-side stays row-major for LDS staging.
// ---------------------------------------------------------------------------
__global__ __launch_bounds__(256) void prep_kernel(
    const float* __restrict__ v, const float* __restrict__ u,
    char* __restrict__ apack, char* __restrict__ uq,
    float* __restrict__ sa, float* __restrict__ sb,
    float* __restrict__ diag, float* __restrict__ rowsum)
{
    const int row  = blockIdx.x * 4 + (threadIdx.x >> 6);
    const int lane = threadIdx.x & 63;
    const float4* vr = reinterpret_cast<const float4*>(v + (size_t)row * DIM);
    const float4* ur = reinterpret_cast<const float4*>(u + (size_t)row * DIM);
    const float4 a0 = vr[lane * 2], a1 = vr[lane * 2 + 1];
    const float4 b0 = ur[lane * 2], b1 = ur[lane * 2 + 1];
    float av[8] = {a0.x, a0.y, a0.z, a0.w, a1.x, a1.y, a1.z, a1.w};
    float bv[8] = {b0.x, b0.y, b0.z, b0.w, b1.x, b1.y, b1.z, b1.w};
    float sv = 0.f, su = 0.f, sd = 0.f, mv = 0.f, mu = 0.f;
#pragma unroll
    for (int i = 0; i < 8; ++i) {
        sv += av[i] * av[i];
        su += bv[i] * bv[i];
        sd += av[i] * bv[i];
        mv = fmaxf(mv, fabsf(av[i]));
        mu = fmaxf(mu, fabsf(bv[i]));
    }
#pragma unroll
    for (int m = 32; m; m >>= 1) {
        sv += __shfl_xor(sv, m);
        su += __shfl_xor(su, m);
        sd += __shfl_xor(sd, m);
        mv = fmaxf(mv, __shfl_xor(mv, m));
        mu = fmaxf(mu, __shfl_xor(mu, m));
    }
    const float rv = 1.0f / fmaxf(sqrtf(sv), 1e-8f);
    const float ru = 1.0f / fmaxf(sqrtf(su), 1e-8f);
    const float qv = 127.0f / fmaxf(mv, 1e-20f);
    const float qu = 127.0f / fmaxf(mu, 1e-20f);
    char8v cv, cu;
#pragma unroll
    for (int i = 0; i < 8; ++i) {
        cv[i] = (char)__float2int_rn(av[i] * qv);
        cu[i] = (char)__float2int_rn(bv[i] * qu);
    }
    // A-pack: this lane's 8 bytes are k = 8*lane .. 8*lane+7
    const size_t dst = (size_t)(row >> 4) * 8192 + (lane >> 4) * 2048 +
                       ((lane >> 3) & 1) * 1024 +
                       ((((lane >> 1) & 3) * 16 + (row & 15)) * 16) +
                       (lane & 1) * 8;
    *reinterpret_cast<char8v*>(apack + dst) = cv;
    reinterpret_cast<char8v*>(uq + (size_t)row * DIM)[lane] = cu;
    if (lane == 0) {
        sa[row] = mv * rv / 127.0f;
        sb[row] = mu * ru / 127.0f;
        diag[row] = sd * rv * ru;
        rowsum[row] = 0.0f;
    }
}

// ---------------------------------------------------------------------------
// Kernel 2: 64-rows-per-wave i8 GEMM, A-frags streamed from global (Apack,
// L2/L3-resident, coalesced lane*16), B in LDS (8 KB tile, double-buffered,
// XOR-swizzled, prefetch-before-compute). Halves the LDS-read invariant
// (1 GB -> 0.5 GB) vs R9 by doubling rows/wave — the A bytes move to the
// parallel VMEM pipe instead of registers (R9: 176 combined regs -> 2
// waves/SIMD was the latency wall).
// Block = 4 waves x 64 rows = 256 rows, sweeping SWEEP=4 col-tiles of 64.
// Grid 32 x 32 = 1024 blocks.
// ---------------------------------------------------------------------------
__global__ __launch_bounds__(256, 2) void simsum_kernel(
    const char* __restrict__ Apack, const char* __restrict__ Bq,
    const float* __restrict__ sa, const float* __restrict__ sb,
    float* __restrict__ rowsum)
{
    __shared__ __align__(16) char ldsB[2][8192];   // [buf][64 cols x 128 B]
    const int tid  = threadIdx.x;
    const int wave = tid >> 6;
    const int lane = tid & 63;
    const int ln15 = lane & 15;
    const int lhi  = lane >> 4;
    const int swz  = (ln15 & 7) << 4;          // read-side XOR (= colrow&7 <<4)

    const int brow = blockIdx.x;               // 0..31 -> 256 rows each
    const int bgrp = blockIdx.y;               // 0..31 -> 4 col-tiles each
    const int growA = brow * 256 + wave * 64;  // this wave's 64 rows
    const int gcol0 = bgrp * (SWEEP * 64);     // this block's 256 cols
    const char* abase = Apack + (size_t)(growA >> 4) * 8192;

    // per-row dequant scale (x 2*log2e) for this thread's 16 rows
    const float C2 = 2.885390081777927f;   // 2 * log2(e)
    float ga[4][4];
#pragma unroll
    for (int m = 0; m < 4; ++m)
#pragma unroll
        for (int rr = 0; rr < 4; ++rr)
            ga[m][rr] = sa[growA + m * 16 + lhi * 4 + rr] * C2;

    float rs[4][4];
#pragma unroll
    for (int m = 0; m < 4; ++m)
#pragma unroll
        for (int rr = 0; rr < 4; ++rr)
            rs[m][rr] = 0.f;

    // staging: 2 gloads/thread cover one 8 KB B tile; linear LDS dest,
    // source column chunk pre-swizzled (G21 both-sides pairing).
    const int r0   = tid >> 3;
    const int sl16 = (((tid & 7) ^ ((tid >> 3) & 7)) << 4);

    auto stageB = [&](int buf, int ct, int t) {
#pragma unroll
        for (int g = 0; g < 2; ++g) {
            const int col = ct * 64 + g * 32 + r0;
            __builtin_amdgcn_global_load_lds(
                AS1(Bq + (size_t)col * ROWB + t * 128 + sl16),
                AS3(&ldsB[buf][g * 4096 + tid * 16]), 16, 0, 0);
        }
    };

    stageB(0, bgrp * SWEEP, 0);
    __syncthreads();

    int buf = 0;
    for (int s = 0; s < SWEEP; ++s) {
        int4v acc[4][4];
#pragma unroll
        for (int m = 0; m < 4; ++m)
#pragma unroll
            for (int n = 0; n < 4; ++n)
                acc[m][n] = (int4v){0, 0, 0, 0};

#pragma unroll
        for (int t = 0; t < NT; ++t) {
            const int nx = s * NT + t + 1;         // next step in sweep
            if (nx < SWEEP * NT) stageB(buf ^ 1, bgrp * SWEEP + (nx >> 2), nx & 3);
#pragma unroll
            for (int kk = 0; kk < 2; ++kk) {
                int4v Af[4], Bf[4];
#pragma unroll
                for (int m = 0; m < 4; ++m)
                    Af[m] = *reinterpret_cast<const int4v*>(
                        abase + (size_t)m * 8192 + t * 2048 + kk * 1024 +
                        lane * 16);
#pragma unroll
                for (int n = 0; n < 4; ++n) {
                    const int c = n * 16 + ln15;
                    Bf[n] = *reinterpret_cast<const int4v*>(
                        &ldsB[buf][c * 128 + ((kk * 64 + lhi * 16) ^ swz)]);
                }
#pragma unroll
                for (int m = 0; m < 4; ++m)
#pragma unroll
                    for (int n = 0; n < 4; ++n)
                        acc[m][n] = __builtin_amdgcn_mfma_i32_16x16x64_i8(
                            Af[m], Bf[n], acc[m][n], 0, 0, 0);
            }
            __syncthreads();   // next B tile staged; this one fully read
            buf ^= 1;
        }

        // fused epilogue for this col-tile: lane-local partial row sums
        float sbv[4];
#pragma unroll
        for (int n = 0; n < 4; ++n)
            sbv[n] = sb[gcol0 + s * 64 + n * 16 + ln15];
#pragma unroll
        for (int m = 0; m < 4; ++m)
#pragma unroll
            for (int rr = 0; rr < 4; ++rr) {
                const float g = ga[m][rr];
#pragma unroll
                for (int n = 0; n < 4; ++n)
                    rs[m][rr] += EXP2((float)acc[m][n][rr] * g * sbv[n]);
            }
    }

    // final cross-lane reduce (cols live across ln15) + one atomic per row
#pragma unroll
    for (int m = 0; m < 4; ++m)
#pragma unroll
        for (int rr = 0; rr < 4; ++rr) {
            float s = rs[m][rr];
            s += __shfl_xor(s, 1);
            s += __shfl_xor(s, 2);
            s += __shfl_xor(s, 4);
            s += __shfl_xor(s, 8);
            if (ln15 == 0)
                atomicAdd(&rowsum[growA + m * 16 + lhi * 4 + rr], s);
        }
}

// ---------------------------------------------------------------------------
// Kernel 3: loss_i = log(exp(2*diag_i) + rowsum_i) - 2*diag_i
// ---------------------------------------------------------------------------
__global__ __launch_bounds__(256) void loss_kernel(
    const float* __restrict__ diag, const float* __restrict__ rowsum,
    float* __restrict__ out)
{
    const int i = blockIdx.x * 256 + threadIdx.x;
    const float d2 = diag[i] * 2.0f;
    out[i] = logf(expf(d2) + rowsum[i]) - d2;
}

extern "C" void kernel_launch(void* const* d_in, const int* in_sizes, int n_in,
                              void* d_out, int out_size, void* d_ws, size_t ws_size,
                              hipStream_t stream) {
    const float* v = (const float*)d_in[0];
    const float* u = (const float*)d_in[1];
    float* out = (float*)d_out;
    char* ws = (char*)d_ws;
    char*  apack  = ws;                                   // 4 MiB (packed A)
    char*  uq     = ws + (size_t)4194304;                 // 4 MiB (row-major B)
    float* sa     = (float*)(ws + (size_t)8388608);       // 32 KiB
    float* sb     = (float*)(ws + (size_t)8388608 + 32768);
    float* diag   = (float*)(ws + (size_t)8388608 + 65536);
    float* rowsum = (float*)(ws + (size_t)8388608 + 98304);

    prep_kernel<<<NROWS / 4, 256, 0, stream>>>(v, u, apack, uq, sa, sb, diag, rowsum);
    dim3 grid(32, 32);
    simsum_kernel<<<grid, 256, 0, stream>>>(apack, uq, sa, sb, rowsum);
    loss_kernel<<<NROWS / 256, 256, 0, stream>>>(diag, rowsum, out);
}

// Round 11
// 66.930 us; speedup vs baseline: 1.2736x; 1.2736x over previous
//
#include <hip/hip_runtime.h>

typedef int   int4v  __attribute__((ext_vector_type(4)));
typedef char  char8v __attribute__((ext_vector_type(8)));

#define NROWS 8192
#define DIM 512
#define ROWB 512           // DIM * 1 byte (i8)
#define NT 4               // K-steps of BK=128

#define AS1(p) ((const __attribute__((address_space(1))) void*)(p))
#define AS3(p) ((__attribute__((address_space(3))) void*)(p))

#if __has_builtin(__builtin_amdgcn_exp2f)
#define EXP2(x) __builtin_amdgcn_exp2f(x)
#else
#define EXP2(x) exp2f(x)
#endif

// ---------------------------------------------------------------------------
// Kernel 1: wave-per-row normalize + i8 quantize + diag + rowsum zero.
// V-side written PACKED in MFMA-fragment order (Apack) so simsum loads
// A-frags with coalesced base+lane*16 (layout correctness-proven in R10):
//   frag (rowgrp g, kstep t, half kk): 1024 B at g*8192 + t*2048 + kk*1024;
//   consuming lane l holds row g*16+(l&15), k-bytes t*128+kk*64+(l>>4)*16.
// ---------------------------------------------------------------------------
__global__ __launch_bounds__(256) void prep_kernel(
    const float* __restrict__ v, const float* __restrict__ u,
    char* __restrict__ apack, char* __restrict__ uq,
    float* __restrict__ sa, float* __restrict__ sb,
    float* __restrict__ diag, float* __restrict__ rowsum)
{
    const int row  = blockIdx.x * 4 + (threadIdx.x >> 6);
    const int lane = threadIdx.x & 63;
    const float4* vr = reinterpret_cast<const float4*>(v + (size_t)row * DIM);
    const float4* ur = reinterpret_cast<const float4*>(u + (size_t)row * DIM);
    const float4 a0 = vr[lane * 2], a1 = vr[lane * 2 + 1];
    const float4 b0 = ur[lane * 2], b1 = ur[lane * 2 + 1];
    float av[8] = {a0.x, a0.y, a0.z, a0.w, a1.x, a1.y, a1.z, a1.w};
    float bv[8] = {b0.x, b0.y, b0.z, b0.w, b1.x, b1.y, b1.z, b1.w};
    float sv = 0.f, su = 0.f, sd = 0.f, mv = 0.f, mu = 0.f;
#pragma unroll
    for (int i = 0; i < 8; ++i) {
        sv += av[i] * av[i];
        su += bv[i] * bv[i];
        sd += av[i] * bv[i];
        mv = fmaxf(mv, fabsf(av[i]));
        mu = fmaxf(mu, fabsf(bv[i]));
    }
#pragma unroll
    for (int m = 32; m; m >>= 1) {
        sv += __shfl_xor(sv, m);
        su += __shfl_xor(su, m);
        sd += __shfl_xor(sd, m);
        mv = fmaxf(mv, __shfl_xor(mv, m));
        mu = fmaxf(mu, __shfl_xor(mu, m));
    }
    const float rv = 1.0f / fmaxf(sqrtf(sv), 1e-8f);
    const float ru = 1.0f / fmaxf(sqrtf(su), 1e-8f);
    const float qv = 127.0f / fmaxf(mv, 1e-20f);
    const float qu = 127.0f / fmaxf(mu, 1e-20f);
    char8v cv, cu;
#pragma unroll
    for (int i = 0; i < 8; ++i) {
        cv[i] = (char)__float2int_rn(av[i] * qv);
        cu[i] = (char)__float2int_rn(bv[i] * qu);
    }
    const size_t dst = (size_t)(row >> 4) * 8192 + (lane >> 4) * 2048 +
                       ((lane >> 3) & 1) * 1024 +
                       ((((lane >> 1) & 3) * 16 + (row & 15)) * 16) +
                       (lane & 1) * 8;
    *reinterpret_cast<char8v*>(apack + dst) = cv;
    reinterpret_cast<char8v*>(uq + (size_t)row * DIM)[lane] = cu;
    if (lane == 0) {
        sa[row] = mv * rv / 127.0f;
        sb[row] = mu * ru / 127.0f;
        diag[row] = sd * rv * ru;
        rowsum[row] = 0.0f;
    }
}

// ---------------------------------------------------------------------------
// Kernel 2: i8 GEMM + fused exp2 rowsum, sized for 4 waves/SIMD.
// Register model (R5-R10 fit: pool ~512/SIMD, waves = 512/(VGPR+AGPR)):
//   A dbuf 32 + acc 32 + Bf 16 + scalars ~35 = ~115 -> 4 waves/SIMD
//   (R7/R9's 176 -> 2 waves/SIMD was the latency wall; R10's 64-row A
//    spilled 320 B/thread).
// Wave = 32 rows x 64 cols. A-frags streamed from Apack (L2), one K-step
// ahead, into NAMED A0/A1 buffers chosen by compile-time t-parity (rule #20:
// no runtime-indexed reg arrays). B in LDS 8 KB x2, XOR-swizzled (0-conflict
// R5-R10), prefetch-before-compute, one __syncthreads per K-step.
// Block = 4 waves x 32 rows = 128 rows; sweeps 4 col-tiles of 64.
// Grid 64 x 32 = 2048 blocks -> 4 blocks/CU co-resident.
// ---------------------------------------------------------------------------
__global__ __launch_bounds__(256, 2) void simsum_kernel(
    const char* __restrict__ Apack, const char* __restrict__ Bq,
    const float* __restrict__ sa, const float* __restrict__ sb,
    float* __restrict__ rowsum)
{
    __shared__ __align__(16) char ldsB[2][8192];   // [buf][64 cols x 128 B]
    const int tid  = threadIdx.x;
    const int wave = tid >> 6;
    const int lane = tid & 63;
    const int ln15 = lane & 15;
    const int lhi  = lane >> 4;
    const int swz  = (ln15 & 7) << 4;          // read-side XOR (= col&7 <<4)

    const int brow = blockIdx.x;               // 0..63 -> 128 rows each
    const int bgrp = blockIdx.y;               // 0..31 -> 4 col-tiles of 64
    const int growA = brow * 128 + wave * 32;  // this wave's 32 rows
    const char* abase = Apack + (size_t)(growA >> 4) * 8192;

    // per-row dequant scale (x 2*log2e) for this thread's 8 rows
    const float C2 = 2.885390081777927f;   // 2 * log2(e)
    float ga[2][4];
#pragma unroll
    for (int m = 0; m < 2; ++m)
#pragma unroll
        for (int rr = 0; rr < 4; ++rr)
            ga[m][rr] = sa[growA + m * 16 + lhi * 4 + rr] * C2;

    float rs[2][4];
#pragma unroll
    for (int m = 0; m < 2; ++m)
#pragma unroll
        for (int rr = 0; rr < 4; ++rr)
            rs[m][rr] = 0.f;

    // A-frag load: frag (m, t, kk) at abase + m*8192 + t*2048 + kk*1024 + lane*16
#define LDA(DST, T) do {                                                      \
    _Pragma("unroll") for (int kk_ = 0; kk_ < 2; ++kk_)                       \
    _Pragma("unroll") for (int m_ = 0; m_ < 2; ++m_)                          \
        DST[kk_][m_] = *reinterpret_cast<const int4v*>(                       \
            abase + (size_t)m_ * 8192 + (T) * 2048 + kk_ * 1024 + lane * 16); \
    } while (0)

    // B staging: 2 gloads/thread cover one 8 KB tile; linear LDS dest,
    // source k-chunk pre-swizzled (G21 both-sides pairing).
    const int r0   = tid >> 3;
    const int sl16 = (((tid & 7) ^ ((tid >> 3) & 7)) << 4);

    auto stageB = [&](int buf, int ct, int t) {
#pragma unroll
        for (int g = 0; g < 2; ++g) {
            const int col = ct * 64 + g * 32 + r0;
            __builtin_amdgcn_global_load_lds(
                AS1(Bq + (size_t)col * ROWB + t * 128 + sl16),
                AS3(&ldsB[buf][g * 4096 + tid * 16]), 16, 0, 0);
        }
    };

    int4v A0[2][2], A1[2][2];
    LDA(A0, 0);
    stageB(0, bgrp * 4, 0);
    __syncthreads();

    int buf = 0;
    for (int s = 0; s < 4; ++s) {
        int4v acc[2][4];
#pragma unroll
        for (int m = 0; m < 2; ++m)
#pragma unroll
            for (int n = 0; n < 4; ++n)
                acc[m][n] = (int4v){0, 0, 0, 0};

#pragma unroll
        for (int t = 0; t < NT; ++t) {
            // prefetch next B tile (global->LDS, other buffer)
            const int nx = s * NT + t + 1;
            if (nx < 4 * NT) stageB(buf ^ 1, bgrp * 4 + (nx >> 2), nx & 3);
            // prefetch next A K-step into the non-current named buffer
            if ((t & 1) == 0) { LDA(A1, (t + 1) & 3); }
            else             { LDA(A0, (t + 1) & 3); }
#pragma unroll
            for (int kk = 0; kk < 2; ++kk) {
                int4v Bf[4];
#pragma unroll
                for (int n = 0; n < 4; ++n) {
                    const int c = n * 16 + ln15;
                    Bf[n] = *reinterpret_cast<const int4v*>(
                        &ldsB[buf][c * 128 + ((kk * 64 + lhi * 16) ^ swz)]);
                }
#pragma unroll
                for (int m = 0; m < 2; ++m)
#pragma unroll
                    for (int n = 0; n < 4; ++n)
                        acc[m][n] = __builtin_amdgcn_mfma_i32_16x16x64_i8(
                            ((t & 1) == 0) ? A0[kk][m] : A1[kk][m],
                            Bf[n], acc[m][n], 0, 0, 0);
            }
            __syncthreads();   // next B tile staged; this one fully read
            buf ^= 1;
        }

        // fused epilogue for this 64-col tile: lane-local partial row sums
        const int ct = bgrp * 4 + s;
        float sbv[4];
#pragma unroll
        for (int n = 0; n < 4; ++n)
            sbv[n] = sb[ct * 64 + n * 16 + ln15];
#pragma unroll
        for (int m = 0; m < 2; ++m)
#pragma unroll
            for (int rr = 0; rr < 4; ++rr) {
                const float g = ga[m][rr];
#pragma unroll
                for (int n = 0; n < 4; ++n)
                    rs[m][rr] += EXP2((float)acc[m][n][rr] * g * sbv[n]);
            }
    }

    // final cross-lane reduce (cols live across ln15) + one atomic per row
#pragma unroll
    for (int m = 0; m < 2; ++m)
#pragma unroll
        for (int rr = 0; rr < 4; ++rr) {
            float s = rs[m][rr];
            s += __shfl_xor(s, 1);
            s += __shfl_xor(s, 2);
            s += __shfl_xor(s, 4);
            s += __shfl_xor(s, 8);
            if (ln15 == 0)
                atomicAdd(&rowsum[growA + m * 16 + lhi * 4 + rr], s);
        }
}

// ---------------------------------------------------------------------------
// Kernel 3: loss_i = log(exp(2*diag_i) + rowsum_i) - 2*diag_i
// ---------------------------------------------------------------------------
__global__ __launch_bounds__(256) void loss_kernel(
    const float* __restrict__ diag, const float* __restrict__ rowsum,
    float* __restrict__ out)
{
    const int i = blockIdx.x * 256 + threadIdx.x;
    const float d2 = diag[i] * 2.0f;
    out[i] = logf(expf(d2) + rowsum[i]) - d2;
}

extern "C" void kernel_launch(void* const* d_in, const int* in_sizes, int n_in,
                              void* d_out, int out_size, void* d_ws, size_t ws_size,
                              hipStream_t stream) {
    const float* v = (const float*)d_in[0];
    const float* u = (const float*)d_in[1];
    float* out = (float*)d_out;
    char* ws = (char*)d_ws;
    char*  apack  = ws;                                   // 4 MiB (packed A)
    char*  uq     = ws + (size_t)4194304;                 // 4 MiB (row-major B)
    float* sa     = (float*)(ws + (size_t)8388608);       // 32 KiB
    float* sb     = (float*)(ws + (size_t)8388608 + 32768);
    float* diag   = (float*)(ws + (size_t)8388608 + 65536);
    float* rowsum = (float*)(ws + (size_t)8388608 + 98304);

    prep_kernel<<<NROWS / 4, 256, 0, stream>>>(v, u, apack, uq, sa, sb, diag, rowsum);
    dim3 grid(64, 32);
    simsum_kernel<<<grid, 256, 0, stream>>>(apack, uq, sa, sb, rowsum);
    loss_kernel<<<NROWS / 256, 256, 0, stream>>>(diag, rowsum, out);
}